// Round 10
// baseline (427.848 us; speedup 1.0000x reference)
//
#include <hip/hip_runtime.h>
#include <hip/hip_bf16.h>
#include <math.h>

typedef unsigned short ushort_t;
typedef __attribute__((ext_vector_type(8))) short short8;
typedef __attribute__((ext_vector_type(4))) short s4v;
typedef __attribute__((ext_vector_type(4))) float float4v;

#define HID 1024
#define NH 8
#define DH 128
#define CHUNK 12
#define PAST 12
#define CTX 24
#define NPOS 25
#define QKVW 3072

__device__ __forceinline__ float bf2f(ushort_t b){
  union{unsigned int u; float f;} x; x.u = ((unsigned int)b)<<16; return x.f;
}
__device__ __forceinline__ ushort_t f2bf(float f){
  union{float f; unsigned int u;} x; x.f = f;
  unsigned int u = x.u;
  unsigned int r = u + 0x7fffu + ((u>>16)&1u);
  return (ushort_t)(r>>16);
}

__device__ __forceinline__ void gload16(const ushort_t* g, ushort_t* l){
  __builtin_amdgcn_global_load_lds(
      (const __attribute__((address_space(1))) unsigned int*)g,
      (__attribute__((address_space(3))) unsigned int*)l,
      16, 0, 0);
}

// f32 -> bf16 conversion, vectorized, grid-stride (n4 = elems/4)
__global__ __launch_bounds__(256) void cvt_f2b(
    const float* __restrict__ in, ushort_t* __restrict__ out, int n4)
{
  for (int i = blockIdx.x*256 + threadIdx.x; i < n4; i += gridDim.x*256){
    float4v v = ((const float4v*)in)[i];
    s4v o;
#pragma unroll
    for (int j=0;j<4;j++) o[j] = (short)f2bf(v[j]);
    ((s4v*)out)[i] = o;
  }
}

// all 4 weights in one launch
__global__ __launch_bounds__(256) void cvt_w4(
    const float* __restrict__ Wq, const float* __restrict__ Wk,
    const float* __restrict__ Wv, const float* __restrict__ Wp,
    ushort_t* __restrict__ Wcat, ushort_t* __restrict__ Wpb, int wsz4)
{
  for (int i = blockIdx.x*256 + threadIdx.x; i < 4*wsz4; i += gridDim.x*256){
    int seg = i / wsz4, off = i - seg*wsz4;
    const float* src = (seg==0) ? Wq : (seg==1) ? Wk : (seg==2) ? Wv : Wp;
    float4v v = ((const float4v*)src)[off];
    s4v o;
#pragma unroll
    for (int j=0;j<4;j++) o[j] = (short)f2bf(v[j]);
    if (seg < 3) ((s4v*)Wcat)[seg*wsz4 + off] = o;
    else         ((s4v*)Wpb)[off] = o;
  }
}

// ===== 128x128 BK=32 3-slot-ring counted-vmcnt GEMM (T3+T4+T5) =====
// C[M,N] = A[M,K] @ W[N,K]^T, bf16 in, f32 accum. 4 waves, wave out 64x64.
// LDS: 3 slots x (A[128x32]+B[128x32]) = 48KB -> 3 blocks/CU.
// Per tile t: s_waitcnt vmcnt(4) [vmcnt(0) at last]; s_barrier;
//   stage t+2 into rotated slot; 12 ds_read_b128 + 32 MFMA (setprio).
// Ledger: at t entry outstanding = {t:4, t+1:4}=8 -> vmcnt(4) retires t.
// WAR: staged slot's previous reads reg-landed before barrier t-1. One
// barrier per tile; vmcnt never drains in the main loop (T4).
// MODE: 0 none, 1 fused qkv epilogue. OUTF: 0 bf16 out, 1 f32 out.
template<int MODE, int OUTF>
__global__ __launch_bounds__(256) void gemm3(
    const ushort_t* __restrict__ A, const ushort_t* __restrict__ W,
    void* __restrict__ Cv, int M, int N, int K,
    const float* __restrict__ pds, float qsc, float ksc)
{
  const int nwg  = gridDim.x;
  const int orig = blockIdx.x;
  const int qch  = nwg >> 3, rch = nwg & 7;
  const int xcd  = orig & 7, idx = orig >> 3;
  const int bid  = (xcd < rch ? xcd*(qch+1) : rch*(qch+1) + (xcd-rch)*qch) + idx;

  const int NT = N >> 7;
  const int m0 = (bid / NT) * 128;
  const int n0 = (bid % NT) * 128;

  const int tid  = threadIdx.x;
  const int w    = tid >> 6, lane = tid & 63;
  const int wm   = w >> 1, wn = w & 1;
  const int lr   = lane & 15;
  const int lg   = lane >> 4;

  __shared__ ushort_t slab[6*128*32];          // 48KB: 3 x (A,B)
  ushort_t* a0 = slab;                 ushort_t* b0 = slab + 128*32;
  ushort_t* a1 = slab + 2*128*32;      ushort_t* b1 = slab + 3*128*32;
  ushort_t* a2 = slab + 4*128*32;      ushort_t* b2 = slab + 5*128*32;

  float4v acc[4][4];
#pragma unroll
  for (int i=0;i<4;i++)
#pragma unroll
    for (int j=0;j<4;j++) acc[i][j] = (float4v)0.0f;

  const int sr = lane >> 2;
  const int sc = (lane & 3) * 8;

  const ushort_t* Ab0 = A + (size_t)(m0 + w*16      + sr)*K + sc;
  const ushort_t* Ab1 = A + (size_t)(m0 + 64 + w*16 + sr)*K + sc;
  const ushort_t* Bb0 = W + (size_t)(n0 + w*16      + sr)*K + sc;
  const ushort_t* Bb1 = W + (size_t)(n0 + 64 + w*16 + sr)*K + sc;

#define STAGE(Abuf, Bbuf, kt) do {                    \
    gload16(Ab0 + (kt), &(Abuf)[(w*16)*32]);          \
    gload16(Ab1 + (kt), &(Abuf)[(64 + w*16)*32]);     \
    gload16(Bb0 + (kt), &(Bbuf)[(w*16)*32]);          \
    gload16(Bb1 + (kt), &(Bbuf)[(64 + w*16)*32]);     \
  } while(0)

#define COMPUTE(Abuf, Bbuf) do {                                             \
    short8 afr[4], bfr[4];                                                   \
    _Pragma("unroll")                                                        \
    for (int i=0;i<4;i++) afr[i] = *(const short8*)&(Abuf)[(wm*64 + i*16 + lr)*32 + lg*8]; \
    _Pragma("unroll")                                                        \
    for (int j=0;j<4;j++) bfr[j] = *(const short8*)&(Bbuf)[(wn*64 + j*16 + lr)*32 + lg*8]; \
    __builtin_amdgcn_s_setprio(1);                                           \
    _Pragma("unroll")                                                        \
    for (int i=0;i<4;i++)                                                    \
      _Pragma("unroll")                                                      \
      for (int j=0;j<4;j++)                                                  \
        acc[i][j] = __builtin_amdgcn_mfma_f32_16x16x32_bf16(afr[i], bfr[j], acc[i][j], 0,0,0); \
    __builtin_amdgcn_s_setprio(0);                                           \
  } while(0)

  const int nt = K >> 5;               // 32 K-tiles
  STAGE(a0, b0, 0);
  STAGE(a1, b1, 32);

  for (int t = 0; t < nt; ++t){
    if (t == nt-1) asm volatile("s_waitcnt vmcnt(0)" ::: "memory");
    else           asm volatile("s_waitcnt vmcnt(4)" ::: "memory");
    asm volatile("s_barrier" ::: "memory");
    if (t+2 < nt) STAGE(a2, b2, (t+2)*32);
    COMPUTE(a0, b0);
    // rotate ring
    ushort_t* ta = a0; a0 = a1; a1 = a2; a2 = ta;
    ushort_t* tb = b0; b0 = b1; b1 = b2; b2 = tb;
  }
#undef STAGE
#undef COMPUTE

  __syncthreads();                     // one-time full drain before re-use

  if (OUTF == 0){
#pragma unroll
    for (int j=0;j<4;j++){
      const int col = wn*64 + j*16 + lr;
      float scale = 1.0f;
      if (MODE==1){
        const int gcol = n0 + col;
        if (gcol < 1024){ float p = pds[gcol & (DH-1)]; scale = qsc * log1pf(expf(p)); }
        else if (gcol < 2048) scale = ksc;
      }
#pragma unroll
      for (int i=0;i<4;i++){
        const int row = wm*64 + i*16 + lg*4;
#pragma unroll
        for (int r=0;r<4;r++)
          slab[(row + r)*128 + col] = f2bf(acc[i][j][r] * scale);
      }
    }
    __syncthreads();
    ushort_t* Crow = (ushort_t*)Cv + (size_t)m0*N + n0;
    const int rr = tid >> 4, sl = (tid & 15)*8;
#pragma unroll
    for (int it=0; it<8; ++it){
      const int row = it*16 + rr;
      *(short8*)&Crow[(size_t)row*N + sl] = *(const short8*)&slab[row*128 + sl];
    }
  } else {
    float* smf = (float*)slab;
    float* Crow = (float*)Cv + (size_t)m0*N + n0;
#pragma unroll
    for (int h2=0; h2<2; ++h2){
      __syncthreads();
      if (wm == h2){
#pragma unroll
        for (int j=0;j<4;j++){
          const int col = wn*64 + j*16 + lr;
#pragma unroll
          for (int i=0;i<4;i++){
            const int row = i*16 + lg*4;
#pragma unroll
            for (int r=0;r<4;r++)
              smf[(row + r)*128 + col] = acc[i][j][r];
          }
        }
      }
      __syncthreads();
      const int rr = tid >> 5, half = ((tid >> 4) & 1)*64, sl = (tid & 15)*4;
#pragma unroll
      for (int it=0; it<8; ++it){
        const int row = it*8 + rr;
        *(float4v*)&Crow[(size_t)(h2*64 + row)*N + half + sl] =
            *(const float4v*)&smf[row*128 + half + sl];
      }
    }
  }
}

// rel[25,1024] = pos_emb[25,1024] @ Wrel[1024,1024]^T   (f32 in, bf16 out)
__global__ __launch_bounds__(256) void relk_kernel(
    const float* __restrict__ pe, const float* __restrict__ Wrel,
    ushort_t* __restrict__ rel)
{
  int gid = blockIdx.x*256 + threadIdx.x;
  if (gid >= NPOS*HID) return;
  int p = gid >> 10, n = gid & 1023;
  const float* a = pe + p*HID;
  const float* w = Wrel + (size_t)n*HID;
  float s = 0.f;
  for (int k=0;k<HID;k+=4){
    float4v av = *(const float4v*)(a+k);
    float4v wv = *(const float4v*)(w+k);
#pragma unroll
    for (int u=0;u<4;u++) s += av[u]*wv[u];
  }
  rel[gid] = f2bf(s);
}

// MFMA attention on fused qkv[row][3072] (q:0, k:+1024, v:+2048).
// block = 4 waves = 4 consecutive chunks of one (b,h).
// rel B-fragments read direct from global (L2-hot; rows 25..31 feed only
// discarded output cols 25..31).
__global__ __launch_bounds__(256) void attn_kernel(
  const ushort_t* __restrict__ qkv, const ushort_t* __restrict__ rel,
  ushort_t* __restrict__ o, int S)
{
  const int n0 = blockIdx.x * 4;
  const int b  = blockIdx.y, h = blockIdx.z;
  const int tid = threadIdx.x;
  const size_t bS = (size_t)b * S;

  __shared__ ushort_t ks[68][136];
  __shared__ ushort_t vt[128][68];
  __shared__ float    sA[4][12][36];
  __shared__ float    sB[4][12][36];
  __shared__ ushort_t Pp[4][16][40];

  const int base = n0*CHUNK - PAST;
  {
    const int r0 = tid >> 4;
    const int c0 = (tid & 15) * 8;
    for (int r = r0; r < 68; r += 16){
      int s = base + r;
      short8 kv = (short8)0, vv = (short8)0;
      if (r < 60 && s >= 0 && s < S){
        kv = *(const short8*)&qkv[(bS + s)*QKVW + 1024 + h*DH + c0];
        vv = *(const short8*)&qkv[(bS + s)*QKVW + 2048 + h*DH + c0];
      }
      *(short8*)&ks[r][c0] = kv;
#pragma unroll
      for (int u=0;u<8;u++) vt[c0+u][r] = (ushort_t)vv[u];
    }
  }
  __syncthreads();

  const int w    = tid >> 6;
  const int lane = tid & 63;
  const int lr   = lane & 15;
  const int lg   = lane >> 4;

  int qrow = (n0 + w)*CHUNK + lr;
  if (qrow >= S) qrow = S - 1;
  const ushort_t* qp = qkv + (bS + qrow)*QKVW + h*DH + lg*8;
  short8 qf[4];
#pragma unroll
  for (int ks2=0; ks2<4; ks2++) qf[ks2] = *(const short8*)(qp + ks2*32);

  // AC = q @ k^T
#pragma unroll
  for (int t0=0; t0<2; t0++){
    float4v acc = (float4v)0.0f;
#pragma unroll
    for (int ks2=0; ks2<4; ks2++){
      short8 kf = *(const short8*)&ks[w*CHUNK + t0*16 + lr][ks2*32 + lg*8];
      acc = __builtin_amdgcn_mfma_f32_16x16x32_bf16(qf[ks2], kf, acc, 0,0,0);
    }
#pragma unroll
    for (int reg=0; reg<4; reg++){
      int cr = lg*4 + reg;
      if (cr < CHUNK) sA[w][cr][t0*16 + lr] = acc[reg];
    }
  }

  // BD = q @ rel^T  (rel fragments direct from global)
  const ushort_t* rp = rel + h*DH;
#pragma unroll
  for (int t0=0; t0<2; t0++){
    float4v acc = (float4v)0.0f;
#pragma unroll
    for (int ks2=0; ks2<4; ks2++){
      short8 rf = *(const short8*)(rp + (size_t)(t0*16 + lr)*HID + ks2*32 + lg*8);
      acc = __builtin_amdgcn_mfma_f32_16x16x32_bf16(qf[ks2], rf, acc, 0,0,0);
    }
#pragma unroll
    for (int reg=0; reg<4; reg++){
      int cr = lg*4 + reg;
      if (cr < CHUNK) sB[w][cr][t0*16 + lr] = acc[reg];
    }
  }

#pragma unroll
  for (int i=0;i<2;i++){
    int idx = i*64 + lane;
    *(s4v*)&Pp[w][idx>>3][(idx&7)*4] = (s4v)0;
  }

  // rel-shift + softcap + softmax (wave-parallel)
  {
    const int c2 = lane >> 5;
    const int t  = lane & 31;
#pragma unroll
    for (int i=0;i<6;i++){
      int c = i*2 + c2;
      float x = -1e30f;
      if (t < CTX){
        int f = c*CTX + t;
        int r = f / NPOS, p = f - r*NPOS;
        x = sA[w][c][t] + sB[w][r][p];
        x = 50.0f * tanhf(x * 0.02f);
      }
      float m = x;
      for (int off=16; off>=1; off>>=1) m = fmaxf(m, __shfl_xor(m, off, 32));
      float e = (t < CTX) ? expf(x - m) : 0.0f;
      float s = e;
      for (int off=16; off>=1; off>>=1) s += __shfl_xor(s, off, 32);
      if (t < CTX) Pp[w][c][t] = f2bf(e / s);
    }
  }

  // PV: O[12x128] = P @ V
  short8 pf = *(const short8*)&Pp[w][lr][lg*8];
  const int orow_base = (n0 + w)*CHUNK;
#pragma unroll
  for (int j=0; j<8; j++){
    int d  = j*16 + lr;
    int tb = w*CHUNK + lg*8;
    s4v b0 = *(const s4v*)&vt[d][tb];
    s4v b1 = *(const s4v*)&vt[d][tb+4];
    short8 bf;
#pragma unroll
    for (int u=0;u<4;u++){ bf[u] = b0[u]; bf[u+4] = b1[u]; }
    float4v a = __builtin_amdgcn_mfma_f32_16x16x32_bf16(pf, bf, (float4v)0.0f, 0,0,0);
#pragma unroll
    for (int reg=0; reg<4; reg++){
      int cr = lg*4 + reg;
      if (cr < CHUNK)
        o[(bS + orow_base + cr)*HID + h*DH + j*16 + lr] = f2bf(a[reg]);
    }
  }
}

extern "C" void kernel_launch(void* const* d_in, const int* in_sizes, int n_in,
                              void* d_out, int out_size, void* d_ws, size_t ws_size,
                              hipStream_t stream)
{
  const float* hs    = (const float*)d_in[0];
  const float* pe    = (const float*)d_in[1];
  const float* Wq    = (const float*)d_in[2];
  const float* Wk    = (const float*)d_in[3];
  const float* Wv    = (const float*)d_in[4];
  const float* Wpost = (const float*)d_in[5];
  const float* Wrel  = (const float*)d_in[6];
  const float* pds   = (const float*)d_in[7];
  float* out = (float*)d_out;

  const int BS = in_sizes[0] / HID;   // 24576
  const int B  = 4;
  const int S  = BS / B;              // 6144
  const int nb = S / CHUNK;           // 512

  const size_t per = (size_t)BS * HID;
  const size_t wsz = (size_t)HID * HID;
  ushort_t* qkv  = (ushort_t*)d_ws;
  ushort_t* at   = qkv  + (size_t)BS * QKVW;
  ushort_t* rel  = at   + per;
  ushort_t* hsb  = rel  + (size_t)NPOS*HID;
  ushort_t* Wcat = hsb  + per;
  ushort_t* Wpb  = Wcat + 3*wsz;

  const float qsc = (float)(pow((double)DH, -0.5) / log(2.0));
  const float ksc = (float)(log(1.0 + exp(1.0)) / log(2.0));

  cvt_f2b<<<2048, 256, 0, stream>>>(hs, hsb, (int)(per/4));
  cvt_w4<<<2048, 256, 0, stream>>>(Wq, Wk, Wv, Wpost, Wcat, Wpb, (int)(wsz/4));

  // fused QKV projection: [24576,1024] @ [3072,1024]^T -> qkv
  gemm3<1,0><<<(BS/128)*(QKVW/128), 256, 0, stream>>>(
      hsb, Wcat, qkv, BS, QKVW, HID, pds, qsc, ksc);
  relk_kernel<<<(NPOS*HID + 255)/256, 256, 0, stream>>>(pe, Wrel, rel);
  attn_kernel<<<dim3(nb/4, B, NH), 256, 0, stream>>>(qkv, rel, at, S);
  // output projection: [24576,1024] @ [1024,1024]^T -> out (f32)
  gemm3<0,1><<<(BS/128)*(HID/128), 256, 0, stream>>>(
      at, Wpb, out, BS, HID, HID, nullptr, 1.0f, 1.0f);
}

// Round 11
// 386.649 us; speedup vs baseline: 1.1066x; 1.1066x over previous
//
#include <hip/hip_runtime.h>
#include <hip/hip_bf16.h>
#include <math.h>

typedef unsigned short ushort_t;
typedef __attribute__((ext_vector_type(8))) short short8;
typedef __attribute__((ext_vector_type(4))) short s4v;
typedef __attribute__((ext_vector_type(4))) float float4v;

#define HID 1024
#define NH 8
#define DH 128
#define CHUNK 12
#define PAST 12
#define CTX 24
#define NPOS 25
#define QKVW 3072

__device__ __forceinline__ float bf2f(ushort_t b){
  union{unsigned int u; float f;} x; x.u = ((unsigned int)b)<<16; return x.f;
}
__device__ __forceinline__ ushort_t f2bf(float f){
  union{float f; unsigned int u;} x; x.f = f;
  unsigned int u = x.u;
  unsigned int r = u + 0x7fffu + ((u>>16)&1u);
  return (ushort_t)(r>>16);
}

__device__ __forceinline__ void gload16(const ushort_t* g, ushort_t* l){
  __builtin_amdgcn_global_load_lds(
      (const __attribute__((address_space(1))) unsigned int*)g,
      (__attribute__((address_space(3))) unsigned int*)l,
      16, 0, 0);
}

// one launch: hs -> hsb, Wq|Wk|Wv -> Wcat, Wpost -> Wpb (f32 -> bf16)
__global__ __launch_bounds__(256) void cvt_all(
    const float* __restrict__ hs, const float* __restrict__ Wq,
    const float* __restrict__ Wk, const float* __restrict__ Wv,
    const float* __restrict__ Wp, ushort_t* __restrict__ hsb,
    ushort_t* __restrict__ Wcat, ushort_t* __restrict__ Wpb, int nhs4)
{
  const int W4 = 262144;               // (1024*1024)/4
  const int total = nhs4 + 4*W4;
  for (int i = blockIdx.x*256 + threadIdx.x; i < total; i += gridDim.x*256){
    const float4v* src; s4v* dst; int off;
    if (i < nhs4){ src = (const float4v*)hs; dst = (s4v*)hsb; off = i; }
    else {
      int j = i - nhs4; int seg = j >> 18; off = j & (W4-1);
      src = (const float4v*)(seg==0?Wq:seg==1?Wk:seg==2?Wv:Wp);
      dst = (seg<3) ? ((s4v*)Wcat) + (size_t)seg*W4 : (s4v*)Wpb;
    }
    float4v v = src[off];
    s4v o;
#pragma unroll
    for (int j2=0;j2<4;j2++) o[j2] = (short)f2bf(v[j2]);
    dst[off] = o;
  }
}

// ===== 128x128 BK=32 3-slot-ring counted-vmcnt GEMM (unchanged, passing) =====
template<int MODE, int OUTF>
__global__ __launch_bounds__(256) void gemm3(
    const ushort_t* __restrict__ A, const ushort_t* __restrict__ W,
    void* __restrict__ Cv, int M, int N, int K,
    const float* __restrict__ pds, float qsc, float ksc)
{
  const int nwg  = gridDim.x;
  const int orig = blockIdx.x;
  const int qch  = nwg >> 3, rch = nwg & 7;
  const int xcd  = orig & 7, idx = orig >> 3;
  const int bid  = (xcd < rch ? xcd*(qch+1) : rch*(qch+1) + (xcd-rch)*qch) + idx;

  const int NT = N >> 7;
  const int m0 = (bid / NT) * 128;
  const int n0 = (bid % NT) * 128;

  const int tid  = threadIdx.x;
  const int w    = tid >> 6, lane = tid & 63;
  const int wm   = w >> 1, wn = w & 1;
  const int lr   = lane & 15;
  const int lg   = lane >> 4;

  __shared__ ushort_t slab[6*128*32];          // 48KB: 3 x (A,B)
  ushort_t* a0 = slab;                 ushort_t* b0 = slab + 128*32;
  ushort_t* a1 = slab + 2*128*32;      ushort_t* b1 = slab + 3*128*32;
  ushort_t* a2 = slab + 4*128*32;      ushort_t* b2 = slab + 5*128*32;

  float4v acc[4][4];
#pragma unroll
  for (int i=0;i<4;i++)
#pragma unroll
    for (int j=0;j<4;j++) acc[i][j] = (float4v)0.0f;

  const int sr = lane >> 2;
  const int sc = (lane & 3) * 8;

  const ushort_t* Ab0 = A + (size_t)(m0 + w*16      + sr)*K + sc;
  const ushort_t* Ab1 = A + (size_t)(m0 + 64 + w*16 + sr)*K + sc;
  const ushort_t* Bb0 = W + (size_t)(n0 + w*16      + sr)*K + sc;
  const ushort_t* Bb1 = W + (size_t)(n0 + 64 + w*16 + sr)*K + sc;

#define STAGE(Abuf, Bbuf, kt) do {                    \
    gload16(Ab0 + (kt), &(Abuf)[(w*16)*32]);          \
    gload16(Ab1 + (kt), &(Abuf)[(64 + w*16)*32]);     \
    gload16(Bb0 + (kt), &(Bbuf)[(w*16)*32]);          \
    gload16(Bb1 + (kt), &(Bbuf)[(64 + w*16)*32]);     \
  } while(0)

#define COMPUTE(Abuf, Bbuf) do {                                             \
    short8 afr[4], bfr[4];                                                   \
    _Pragma("unroll")                                                        \
    for (int i=0;i<4;i++) afr[i] = *(const short8*)&(Abuf)[(wm*64 + i*16 + lr)*32 + lg*8]; \
    _Pragma("unroll")                                                        \
    for (int j=0;j<4;j++) bfr[j] = *(const short8*)&(Bbuf)[(wn*64 + j*16 + lr)*32 + lg*8]; \
    __builtin_amdgcn_s_setprio(1);                                           \
    _Pragma("unroll")                                                        \
    for (int i=0;i<4;i++)                                                    \
      _Pragma("unroll")                                                      \
      for (int j=0;j<4;j++)                                                  \
        acc[i][j] = __builtin_amdgcn_mfma_f32_16x16x32_bf16(afr[i], bfr[j], acc[i][j], 0,0,0); \
    __builtin_amdgcn_s_setprio(0);                                           \
  } while(0)

  const int nt = K >> 5;
  STAGE(a0, b0, 0);
  STAGE(a1, b1, 32);

  for (int t = 0; t < nt; ++t){
    if (t == nt-1) asm volatile("s_waitcnt vmcnt(0)" ::: "memory");
    else           asm volatile("s_waitcnt vmcnt(4)" ::: "memory");
    asm volatile("s_barrier" ::: "memory");
    if (t+2 < nt) STAGE(a2, b2, (t+2)*32);
    COMPUTE(a0, b0);
    ushort_t* ta = a0; a0 = a1; a1 = a2; a2 = ta;
    ushort_t* tb = b0; b0 = b1; b1 = b2; b2 = tb;
  }
#undef STAGE
#undef COMPUTE

  __syncthreads();

  if (OUTF == 0){
#pragma unroll
    for (int j=0;j<4;j++){
      const int col = wn*64 + j*16 + lr;
      float scale = 1.0f;
      if (MODE==1){
        const int gcol = n0 + col;
        if (gcol < 1024){ float p = pds[gcol & (DH-1)]; scale = qsc * log1pf(expf(p)); }
        else if (gcol < 2048) scale = ksc;
      }
#pragma unroll
      for (int i=0;i<4;i++){
        const int row = wm*64 + i*16 + lg*4;
#pragma unroll
        for (int r=0;r<4;r++)
          slab[(row + r)*128 + col] = f2bf(acc[i][j][r] * scale);
      }
    }
    __syncthreads();
    ushort_t* Crow = (ushort_t*)Cv + (size_t)m0*N + n0;
    const int rr = tid >> 4, sl = (tid & 15)*8;
#pragma unroll
    for (int it=0; it<8; ++it){
      const int row = it*16 + rr;
      *(short8*)&Crow[(size_t)row*N + sl] = *(const short8*)&slab[row*128 + sl];
    }
  } else {
    float* smf = (float*)slab;
    float* Crow = (float*)Cv + (size_t)m0*N + n0;
#pragma unroll
    for (int h2=0; h2<2; ++h2){
      __syncthreads();
      if (wm == h2){
#pragma unroll
        for (int j=0;j<4;j++){
          const int col = wn*64 + j*16 + lr;
#pragma unroll
          for (int i=0;i<4;i++){
            const int row = i*16 + lg*4;
#pragma unroll
            for (int r=0;r<4;r++)
              smf[(row + r)*128 + col] = acc[i][j][r];
          }
        }
      }
      __syncthreads();
      const int rr = tid >> 5, half = ((tid >> 4) & 1)*64, sl = (tid & 15)*4;
#pragma unroll
      for (int it=0; it<8; ++it){
        const int row = it*8 + rr;
        *(float4v*)&Crow[(size_t)(h2*64 + row)*N + half + sl] =
            *(const float4v*)&smf[row*128 + half + sl];
      }
    }
  }
}

// rel[25,1024] = pe[25,1024] @ Wrel^T, 2-way K-split + shfl combine
__global__ __launch_bounds__(256) void relk2(
    const float* __restrict__ pe, const float* __restrict__ Wrel,
    ushort_t* __restrict__ rel)
{
  int g = blockIdx.x*256 + threadIdx.x;    // 51200 threads
  int idx = g >> 1, par = g & 1;
  if (idx >= NPOS*HID) return;
  int p = idx >> 10, n = idx & 1023;
  const float* a = pe + p*HID + par*512;
  const float* w = Wrel + (size_t)n*HID + par*512;
  float s = 0.f;
  for (int k=0;k<512;k+=4){
    float4v av = *(const float4v*)(a+k);
    float4v wv = *(const float4v*)(w+k);
#pragma unroll
    for (int u=0;u<4;u++) s += av[u]*wv[u];
  }
  s += __shfl_xor(s, 1, 64);
  if (!par) rel[idx] = f2bf(s);
}

// MFMA attention, LDS lifetime-aliased: 49.6KB -> 3 blocks/CU.
// Phases: stage(ks,vt,rs); BD(reads rs, writes sB); bar; AC(reads ks,
// writes sA=alias(rs)); bar; softmax(reads sA,sB, writes Pp=alias(ks)); PV.
__global__ __launch_bounds__(256) void attn_kernel(
  const ushort_t* __restrict__ qkv, const ushort_t* __restrict__ rel,
  ushort_t* __restrict__ o, int S)
{
  const int n0 = blockIdx.x * 4;
  const int b  = blockIdx.y, h = blockIdx.z;
  const int tid = threadIdx.x;
  const size_t bS = (size_t)b * S;

  __shared__ ushort_t lds[24800];          // 49,600 B
  ushort_t* ks = lds;                      // [68][136] (Pp aliases head later)
  ushort_t* vt = lds + 9248;               // [128][68]
  float*    sB = (float*)(lds + 17952);    // [4][12][26] f32
  ushort_t* rs = lds + 20448;              // [32][136]  (sA aliases later)
  float*    sA = (float*)(lds + 20448);

  const int base = n0*CHUNK - PAST;
  {
    const int r0 = tid >> 4;
    const int c0 = (tid & 15) * 8;
    for (int r = r0; r < 68; r += 16){
      int s = base + r;
      short8 kv = (short8)0, vv = (short8)0;
      if (r < 60 && s >= 0 && s < S){
        kv = *(const short8*)&qkv[(bS + s)*QKVW + 1024 + h*DH + c0];
        vv = *(const short8*)&qkv[(bS + s)*QKVW + 2048 + h*DH + c0];
      }
      *(short8*)&ks[r*136 + c0] = kv;
#pragma unroll
      for (int u=0;u<8;u++) vt[(c0+u)*68 + r] = (ushort_t)vv[u];
    }
    for (int r = r0; r < 32; r += 16){
      short8 rv = (short8)0;
      if (r < NPOS) rv = *(const short8*)&rel[r*HID + h*DH + c0];
      *(short8*)&rs[r*136 + c0] = rv;
    }
  }
  __syncthreads();

  const int w    = tid >> 6;
  const int lane = tid & 63;
  const int lr   = lane & 15;
  const int lg   = lane >> 4;

  float*    sAw = sA + w*312;              // 12*26
  float*    sBw = sB + w*312;
  ushort_t* Ppw = lds + w*640;             // [16][40] in ks space

  int qrow = (n0 + w)*CHUNK + lr;
  if (qrow >= S) qrow = S - 1;
  const ushort_t* qp = qkv + (bS + qrow)*QKVW + h*DH + lg*8;
  short8 qf[4];
#pragma unroll
  for (int ks2=0; ks2<4; ks2++) qf[ks2] = *(const short8*)(qp + ks2*32);

  // ---- BD = q @ rel^T (reads rs, writes sB) ----
#pragma unroll
  for (int t0=0; t0<2; t0++){
    float4v acc = (float4v)0.0f;
#pragma unroll
    for (int ks2=0; ks2<4; ks2++){
      short8 rf = *(const short8*)&rs[(t0*16 + lr)*136 + ks2*32 + lg*8];
      acc = __builtin_amdgcn_mfma_f32_16x16x32_bf16(qf[ks2], rf, acc, 0,0,0);
    }
    const int p = t0*16 + lr;
#pragma unroll
    for (int reg=0; reg<4; reg++){
      int cr = lg*4 + reg;
      if (cr < CHUNK && p < NPOS) sBw[cr*26 + p] = acc[reg];
    }
  }
  __syncthreads();                         // all rs reads done -> sA may write

  // ---- AC = q @ k^T (reads ks, writes sA = alias of rs) ----
#pragma unroll
  for (int t0=0; t0<2; t0++){
    float4v acc = (float4v)0.0f;
#pragma unroll
    for (int ks2=0; ks2<4; ks2++){
      short8 kf = *(const short8*)&ks[(w*CHUNK + t0*16 + lr)*136 + ks2*32 + lg*8];
      acc = __builtin_amdgcn_mfma_f32_16x16x32_bf16(qf[ks2], kf, acc, 0,0,0);
    }
    const int t = t0*16 + lr;
#pragma unroll
    for (int reg=0; reg<4; reg++){
      int cr = lg*4 + reg;
      if (cr < CHUNK && t < CTX) sAw[cr*26 + t] = acc[reg];
    }
  }
  __syncthreads();                         // all ks reads done -> Pp may write

  // zero P cols 24..31 rows 0..11 (rows 12..15 feed discarded C rows)
  if (lane < CHUNK) *(short8*)&Ppw[lane*40 + 24] = (short8)0;

  // ---- rel-shift + softcap + softmax ----
  {
    const int c2 = lane >> 5;
    const int t  = lane & 31;
#pragma unroll
    for (int i=0;i<6;i++){
      int c = i*2 + c2;
      float x = -1e30f;
      if (t < CTX){
        int f = c*CTX + t;
        int r = f / NPOS, p = f - r*NPOS;
        x = sAw[c*26 + t] + sBw[r*26 + p];
        x = 50.0f * tanhf(x * 0.02f);
      }
      float m = x;
      for (int off=16; off>=1; off>>=1) m = fmaxf(m, __shfl_xor(m, off, 32));
      float e = (t < CTX) ? expf(x - m) : 0.0f;
      float s = e;
      for (int off=16; off>=1; off>>=1) s += __shfl_xor(s, off, 32);
      if (t < CTX) Ppw[c*40 + t] = f2bf(e / s);
    }
  }

  // ---- PV: O[12x128] = P @ V ----
  short8 pf = *(const short8*)&Ppw[lr*40 + lg*8];
  const int orow_base = (n0 + w)*CHUNK;
#pragma unroll
  for (int j=0; j<8; j++){
    int d  = j*16 + lr;
    int tb = w*CHUNK + lg*8;
    s4v b0 = *(const s4v*)&vt[d*68 + tb];
    s4v b1 = *(const s4v*)&vt[d*68 + tb + 4];
    short8 bf;
#pragma unroll
    for (int u=0;u<4;u++){ bf[u] = b0[u]; bf[u+4] = b1[u]; }
    float4v a = __builtin_amdgcn_mfma_f32_16x16x32_bf16(pf, bf, (float4v)0.0f, 0,0,0);
#pragma unroll
    for (int reg=0; reg<4; reg++){
      int cr = lg*4 + reg;
      if (cr < CHUNK)
        o[(bS + orow_base + cr)*HID + h*DH + j*16 + lr] = f2bf(a[reg]);
    }
  }
}

extern "C" void kernel_launch(void* const* d_in, const int* in_sizes, int n_in,
                              void* d_out, int out_size, void* d_ws, size_t ws_size,
                              hipStream_t stream)
{
  const float* hs    = (const float*)d_in[0];
  const float* pe    = (const float*)d_in[1];
  const float* Wq    = (const float*)d_in[2];
  const float* Wk    = (const float*)d_in[3];
  const float* Wv    = (const float*)d_in[4];
  const float* Wpost = (const float*)d_in[5];
  const float* Wrel  = (const float*)d_in[6];
  const float* pds   = (const float*)d_in[7];
  float* out = (float*)d_out;

  const int BS = in_sizes[0] / HID;   // 24576
  const int B  = 4;
  const int S  = BS / B;              // 6144
  const int nb = S / CHUNK;           // 512

  const size_t per = (size_t)BS * HID;
  const size_t wsz = (size_t)HID * HID;
  ushort_t* qkv  = (ushort_t*)d_ws;
  ushort_t* at   = qkv  + (size_t)BS * QKVW;
  ushort_t* rel  = at   + per;
  ushort_t* hsb  = rel  + (size_t)NPOS*HID;
  ushort_t* Wcat = hsb  + per;
  ushort_t* Wpb  = Wcat + 3*wsz;

  const float qsc = (float)(pow((double)DH, -0.5) / log(2.0));
  const float ksc = (float)(log(1.0 + exp(1.0)) / log(2.0));

  cvt_all<<<4096, 256, 0, stream>>>(hs, Wq, Wk, Wv, Wpost, hsb, Wcat, Wpb,
                                    (int)(per/4));
  relk2<<<200, 256, 0, stream>>>(pe, Wrel, rel);

  // fused QKV projection: [24576,1024] @ [3072,1024]^T -> qkv
  gemm3<1,0><<<(BS/128)*(QKVW/128), 256, 0, stream>>>(
      hsb, Wcat, qkv, BS, QKVW, HID, pds, qsc, ksc);
  attn_kernel<<<dim3(nb/4, B, NH), 256, 0, stream>>>(qkv, rel, at, S);
  // output projection: [24576,1024] @ [1024,1024]^T -> out (f32)
  gemm3<0,1><<<(BS/128)*(HID/128), 256, 0, stream>>>(
      at, Wpb, out, BS, HID, HID, nullptr, 1.0f, 1.0f);
}

// Round 12
// 383.007 us; speedup vs baseline: 1.1171x; 1.0095x over previous
//
#include <hip/hip_runtime.h>
#include <hip/hip_bf16.h>
#include <math.h>

typedef unsigned short ushort_t;
typedef __attribute__((ext_vector_type(8))) short short8;
typedef __attribute__((ext_vector_type(4))) short s4v;
typedef __attribute__((ext_vector_type(4))) float float4v;

#define HID 1024
#define NH 8
#define DH 128
#define CHUNK 12
#define PAST 12
#define CTX 24
#define NPOS 25
#define QKVW 3072

__device__ __forceinline__ float bf2f(ushort_t b){
  union{unsigned int u; float f;} x; x.u = ((unsigned int)b)<<16; return x.f;
}
__device__ __forceinline__ ushort_t f2bf(float f){
  union{float f; unsigned int u;} x; x.f = f;
  unsigned int u = x.u;
  unsigned int r = u + 0x7fffu + ((u>>16)&1u);
  return (ushort_t)(r>>16);
}

__device__ __forceinline__ void gload16(const ushort_t* g, ushort_t* l){
  __builtin_amdgcn_global_load_lds(
      (const __attribute__((address_space(1))) unsigned int*)g,
      (__attribute__((address_space(3))) unsigned int*)l,
      16, 0, 0);
}

// one launch: hs -> hsb, Wq|Wk|Wv -> Wcat, Wpost -> Wpb (f32 -> bf16)
__global__ __launch_bounds__(256) void cvt_all(
    const float* __restrict__ hs, const float* __restrict__ Wq,
    const float* __restrict__ Wk, const float* __restrict__ Wv,
    const float* __restrict__ Wp, ushort_t* __restrict__ hsb,
    ushort_t* __restrict__ Wcat, ushort_t* __restrict__ Wpb, int nhs4)
{
  const int W4 = 262144;               // (1024*1024)/4
  const int total = nhs4 + 4*W4;
  for (int i = blockIdx.x*256 + threadIdx.x; i < total; i += gridDim.x*256){
    const float4v* src; s4v* dst; int off;
    if (i < nhs4){ src = (const float4v*)hs; dst = (s4v*)hsb; off = i; }
    else {
      int j = i - nhs4; int seg = j >> 18; off = j & (W4-1);
      src = (const float4v*)(seg==0?Wq:seg==1?Wk:seg==2?Wv:Wp);
      dst = (seg<3) ? ((s4v*)Wcat) + (size_t)seg*W4 : (s4v*)Wpb;
    }
    float4v v = src[off];
    s4v o;
#pragma unroll
    for (int j2=0;j2<4;j2++) o[j2] = (short)f2bf(v[j2]);
    dst[off] = o;
  }
}

// ===== 128x128 BK=32 3-slot-ring counted-vmcnt GEMM + 2-way bank placement =====
// LDS tile layout: [8 groups of 16 rows][64 x 16B-slots], slot index
// g(rl,s) = (rl>>1)*8 + (rl&1)*4 + (s ^ ((rl>>1)&3))  -> for fixed s the 16
// rows cover all 8 bank-groups twice (2-way, free). gload_lds dest stays
// linear; the per-lane GLOBAL source is permuted by the inverse; ds_read
// applies g() on the index. (rule-21: source-permutation == read-permutation)
template<int MODE, int OUTF>
__global__ __launch_bounds__(256) void gemm3(
    const ushort_t* __restrict__ A, const ushort_t* __restrict__ W,
    void* __restrict__ Cv, int M, int N, int K,
    const float* __restrict__ pds, float qsc, float ksc)
{
  const int nwg  = gridDim.x;
  const int orig = blockIdx.x;
  const int qch  = nwg >> 3, rch = nwg & 7;
  const int xcd  = orig & 7, idx = orig >> 3;
  const int bid  = (xcd < rch ? xcd*(qch+1) : rch*(qch+1) + (xcd-rch)*qch) + idx;

  const int NT = N >> 7;
  const int m0 = (bid / NT) * 128;
  const int n0 = (bid % NT) * 128;

  const int tid  = threadIdx.x;
  const int w    = tid >> 6, lane = tid & 63;
  const int wm   = w >> 1, wn = w & 1;
  const int lr   = lane & 15;
  const int lg   = lane >> 4;

  __shared__ ushort_t slab[6*128*32];          // 48KB: 3 x (A,B)
  ushort_t* a0 = slab;                 ushort_t* b0 = slab + 128*32;
  ushort_t* a1 = slab + 2*128*32;      ushort_t* b1 = slab + 3*128*32;
  ushort_t* a2 = slab + 4*128*32;      ushort_t* b2 = slab + 5*128*32;

  float4v acc[4][4];
#pragma unroll
  for (int i=0;i<4;i++)
#pragma unroll
    for (int j=0;j<4;j++) acc[i][j] = (float4v)0.0f;

  // staging source permutation (inverse of g): lane l covers
  // row = (l>>3)*2 + ((l>>2)&1), slot = (l&3) ^ ((l>>3)&3)
  const int sr = ((lane >> 3) << 1) | ((lane >> 2) & 1);
  const int sc = ((lane & 3) ^ ((lane >> 3) & 3)) * 8;

  // read-side permuted slot index (ushorts), lane-constant
  const int fidx = ((lr >> 1)*8 + (lr & 1)*4 + (lg ^ ((lr >> 1) & 3))) * 8;

  const ushort_t* Ab0 = A + (size_t)(m0 + w*16      + sr)*K + sc;
  const ushort_t* Ab1 = A + (size_t)(m0 + 64 + w*16 + sr)*K + sc;
  const ushort_t* Bb0 = W + (size_t)(n0 + w*16      + sr)*K + sc;
  const ushort_t* Bb1 = W + (size_t)(n0 + 64 + w*16 + sr)*K + sc;

#define STAGE(Abuf, Bbuf, kt) do {                    \
    gload16(Ab0 + (kt), &(Abuf)[(w*16)*32]);          \
    gload16(Ab1 + (kt), &(Abuf)[(64 + w*16)*32]);     \
    gload16(Bb0 + (kt), &(Bbuf)[(w*16)*32]);          \
    gload16(Bb1 + (kt), &(Bbuf)[(64 + w*16)*32]);     \
  } while(0)

#define COMPUTE(Abuf, Bbuf) do {                                             \
    short8 afr[4], bfr[4];                                                   \
    _Pragma("unroll")                                                        \
    for (int i=0;i<4;i++) afr[i] = *(const short8*)&(Abuf)[(wm*4 + i)*512 + fidx]; \
    _Pragma("unroll")                                                        \
    for (int j=0;j<4;j++) bfr[j] = *(const short8*)&(Bbuf)[(wn*4 + j)*512 + fidx]; \
    __builtin_amdgcn_s_setprio(1);                                           \
    _Pragma("unroll")                                                        \
    for (int i=0;i<4;i++)                                                    \
      _Pragma("unroll")                                                      \
      for (int j=0;j<4;j++)                                                  \
        acc[i][j] = __builtin_amdgcn_mfma_f32_16x16x32_bf16(afr[i], bfr[j], acc[i][j], 0,0,0); \
    __builtin_amdgcn_s_setprio(0);                                           \
  } while(0)

  const int nt = K >> 5;
  STAGE(a0, b0, 0);
  STAGE(a1, b1, 32);

  for (int t = 0; t < nt; ++t){
    if (t == nt-1) asm volatile("s_waitcnt vmcnt(0)" ::: "memory");
    else           asm volatile("s_waitcnt vmcnt(4)" ::: "memory");
    asm volatile("s_barrier" ::: "memory");
    if (t+2 < nt) STAGE(a2, b2, (t+2)*32);
    COMPUTE(a0, b0);
    ushort_t* ta = a0; a0 = a1; a1 = a2; a2 = ta;
    ushort_t* tb = b0; b0 = b1; b1 = b2; b2 = tb;
  }
#undef STAGE
#undef COMPUTE

  __syncthreads();

  if (OUTF == 0){
#pragma unroll
    for (int j=0;j<4;j++){
      const int col = wn*64 + j*16 + lr;
      float scale = 1.0f;
      if (MODE==1){
        const int gcol = n0 + col;
        if (gcol < 1024){ float p = pds[gcol & (DH-1)]; scale = qsc * log1pf(expf(p)); }
        else if (gcol < 2048) scale = ksc;
      }
#pragma unroll
      for (int i=0;i<4;i++){
        const int row = wm*64 + i*16 + lg*4;
#pragma unroll
        for (int r=0;r<4;r++)
          slab[(row + r)*128 + col] = f2bf(acc[i][j][r] * scale);
      }
    }
    __syncthreads();
    ushort_t* Crow = (ushort_t*)Cv + (size_t)m0*N + n0;
    const int rr = tid >> 4, sl = (tid & 15)*8;
#pragma unroll
    for (int it=0; it<8; ++it){
      const int row = it*16 + rr;
      *(short8*)&Crow[(size_t)row*N + sl] = *(const short8*)&slab[row*128 + sl];
    }
  } else {
    float* smf = (float*)slab;
    float* Crow = (float*)Cv + (size_t)m0*N + n0;
#pragma unroll
    for (int h2=0; h2<2; ++h2){
      __syncthreads();
      if (wm == h2){
#pragma unroll
        for (int j=0;j<4;j++){
          const int col = wn*64 + j*16 + lr;
#pragma unroll
          for (int i=0;i<4;i++){
            const int row = i*16 + lg*4;
#pragma unroll
            for (int r=0;r<4;r++)
              smf[(row + r)*128 + col] = acc[i][j][r];
          }
        }
      }
      __syncthreads();
      const int rr = tid >> 5, half = ((tid >> 4) & 1)*64, sl = (tid & 15)*4;
#pragma unroll
      for (int it=0; it<8; ++it){
        const int row = it*8 + rr;
        *(float4v*)&Crow[(size_t)(h2*64 + row)*N + half + sl] =
            *(const float4v*)&smf[row*128 + half + sl];
      }
    }
  }
}

// rel[25,1024] = pe[25,1024] @ Wrel^T, 2-way K-split + shfl combine
__global__ __launch_bounds__(256) void relk2(
    const float* __restrict__ pe, const float* __restrict__ Wrel,
    ushort_t* __restrict__ rel)
{
  int g = blockIdx.x*256 + threadIdx.x;
  int idx = g >> 1, par = g & 1;
  if (idx >= NPOS*HID) return;
  int p = idx >> 10, n = idx & 1023;
  const float* a = pe + p*HID + par*512;
  const float* w = Wrel + (size_t)n*HID + par*512;
  float s = 0.f;
  for (int k=0;k<512;k+=4){
    float4v av = *(const float4v*)(a+k);
    float4v wv = *(const float4v*)(w+k);
#pragma unroll
    for (int u=0;u<4;u++) s += av[u]*wv[u];
  }
  s += __shfl_xor(s, 1, 64);
  if (!par) rel[idx] = f2bf(s);
}

// MFMA attention, LDS lifetime-aliased: 49.6KB -> 3 blocks/CU. (passing r11)
__global__ __launch_bounds__(256) void attn_kernel(
  const ushort_t* __restrict__ qkv, const ushort_t* __restrict__ rel,
  ushort_t* __restrict__ o, int S)
{
  const int n0 = blockIdx.x * 4;
  const int b  = blockIdx.y, h = blockIdx.z;
  const int tid = threadIdx.x;
  const size_t bS = (size_t)b * S;

  __shared__ ushort_t lds[24800];
  ushort_t* ks = lds;
  ushort_t* vt = lds + 9248;
  float*    sB = (float*)(lds + 17952);
  ushort_t* rs = lds + 20448;
  float*    sA = (float*)(lds + 20448);

  const int base = n0*CHUNK - PAST;
  {
    const int r0 = tid >> 4;
    const int c0 = (tid & 15) * 8;
    for (int r = r0; r < 68; r += 16){
      int s = base + r;
      short8 kv = (short8)0, vv = (short8)0;
      if (r < 60 && s >= 0 && s < S){
        kv = *(const short8*)&qkv[(bS + s)*QKVW + 1024 + h*DH + c0];
        vv = *(const short8*)&qkv[(bS + s)*QKVW + 2048 + h*DH + c0];
      }
      *(short8*)&ks[r*136 + c0] = kv;
#pragma unroll
      for (int u=0;u<8;u++) vt[(c0+u)*68 + r] = (ushort_t)vv[u];
    }
    for (int r = r0; r < 32; r += 16){
      short8 rv = (short8)0;
      if (r < NPOS) rv = *(const short8*)&rel[r*HID + h*DH + c0];
      *(short8*)&rs[r*136 + c0] = rv;
    }
  }
  __syncthreads();

  const int w    = tid >> 6;
  const int lane = tid & 63;
  const int lr   = lane & 15;
  const int lg   = lane >> 4;

  float*    sAw = sA + w*312;
  float*    sBw = sB + w*312;
  ushort_t* Ppw = lds + w*640;

  int qrow = (n0 + w)*CHUNK + lr;
  if (qrow >= S) qrow = S - 1;
  const ushort_t* qp = qkv + (bS + qrow)*QKVW + h*DH + lg*8;
  short8 qf[4];
#pragma unroll
  for (int ks2=0; ks2<4; ks2++) qf[ks2] = *(const short8*)(qp + ks2*32);

  // BD = q @ rel^T
#pragma unroll
  for (int t0=0; t0<2; t0++){
    float4v acc = (float4v)0.0f;
#pragma unroll
    for (int ks2=0; ks2<4; ks2++){
      short8 rf = *(const short8*)&rs[(t0*16 + lr)*136 + ks2*32 + lg*8];
      acc = __builtin_amdgcn_mfma_f32_16x16x32_bf16(qf[ks2], rf, acc, 0,0,0);
    }
    const int p = t0*16 + lr;
#pragma unroll
    for (int reg=0; reg<4; reg++){
      int cr = lg*4 + reg;
      if (cr < CHUNK && p < NPOS) sBw[cr*26 + p] = acc[reg];
    }
  }
  __syncthreads();

  // AC = q @ k^T (sA aliases rs)
#pragma unroll
  for (int t0=0; t0<2; t0++){
    float4v acc = (float4v)0.0f;
#pragma unroll
    for (int ks2=0; ks2<4; ks2++){
      short8 kf = *(const short8*)&ks[(w*CHUNK + t0*16 + lr)*136 + ks2*32 + lg*8];
      acc = __builtin_amdgcn_mfma_f32_16x16x32_bf16(qf[ks2], kf, acc, 0,0,0);
    }
    const int t = t0*16 + lr;
#pragma unroll
    for (int reg=0; reg<4; reg++){
      int cr = lg*4 + reg;
      if (cr < CHUNK && t < CTX) sAw[cr*26 + t] = acc[reg];
    }
  }
  __syncthreads();

  if (lane < CHUNK) *(short8*)&Ppw[lane*40 + 24] = (short8)0;

  {
    const int c2 = lane >> 5;
    const int t  = lane & 31;
#pragma unroll
    for (int i=0;i<6;i++){
      int c = i*2 + c2;
      float x = -1e30f;
      if (t < CTX){
        int f = c*CTX + t;
        int r = f / NPOS, p = f - r*NPOS;
        x = sAw[c*26 + t] + sBw[r*26 + p];
        x = 50.0f * tanhf(x * 0.02f);
      }
      float m = x;
      for (int off=16; off>=1; off>>=1) m = fmaxf(m, __shfl_xor(m, off, 32));
      float e = (t < CTX) ? expf(x - m) : 0.0f;
      float s = e;
      for (int off=16; off>=1; off>>=1) s += __shfl_xor(s, off, 32);
      if (t < CTX) Ppw[c*40 + t] = f2bf(e / s);
    }
  }

  short8 pf = *(const short8*)&Ppw[lr*40 + lg*8];
  const int orow_base = (n0 + w)*CHUNK;
#pragma unroll
  for (int j=0; j<8; j++){
    int d  = j*16 + lr;
    int tb = w*CHUNK + lg*8;
    s4v b0 = *(const s4v*)&vt[d*68 + tb];
    s4v b1 = *(const s4v*)&vt[d*68 + tb + 4];
    short8 bf;
#pragma unroll
    for (int u=0;u<4;u++){ bf[u] = b0[u]; bf[u+4] = b1[u]; }
    float4v a = __builtin_amdgcn_mfma_f32_16x16x32_bf16(pf, bf, (float4v)0.0f, 0,0,0);
#pragma unroll
    for (int reg=0; reg<4; reg++){
      int cr = lg*4 + reg;
      if (cr < CHUNK)
        o[(bS + orow_base + cr)*HID + h*DH + j*16 + lr] = f2bf(a[reg]);
    }
  }
}

extern "C" void kernel_launch(void* const* d_in, const int* in_sizes, int n_in,
                              void* d_out, int out_size, void* d_ws, size_t ws_size,
                              hipStream_t stream)
{
  const float* hs    = (const float*)d_in[0];
  const float* pe    = (const float*)d_in[1];
  const float* Wq    = (const float*)d_in[2];
  const float* Wk    = (const float*)d_in[3];
  const float* Wv    = (const float*)d_in[4];
  const float* Wpost = (const float*)d_in[5];
  const float* Wrel  = (const float*)d_in[6];
  const float* pds   = (const float*)d_in[7];
  float* out = (float*)d_out;

  const int BS = in_sizes[0] / HID;   // 24576
  const int B  = 4;
  const int S  = BS / B;              // 6144
  const int nb = S / CHUNK;           // 512

  const size_t per = (size_t)BS * HID;
  const size_t wsz = (size_t)HID * HID;
  ushort_t* qkv  = (ushort_t*)d_ws;
  ushort_t* at   = qkv  + (size_t)BS * QKVW;
  ushort_t* rel  = at   + per;
  ushort_t* hsb  = rel  + (size_t)NPOS*HID;
  ushort_t* Wcat = hsb  + per;
  ushort_t* Wpb  = Wcat + 3*wsz;

  const float qsc = (float)(pow((double)DH, -0.5) / log(2.0));
  const float ksc = (float)(log(1.0 + exp(1.0)) / log(2.0));

  cvt_all<<<4096, 256, 0, stream>>>(hs, Wq, Wk, Wv, Wpost, hsb, Wcat, Wpb,
                                    (int)(per/4));
  relk2<<<200, 256, 0, stream>>>(pe, Wrel, rel);

  gemm3<1,0><<<(BS/128)*(QKVW/128), 256, 0, stream>>>(
      hsb, Wcat, qkv, BS, QKVW, HID, pds, qsc, ksc);
  attn_kernel<<<dim3(nb/4, B, NH), 256, 0, stream>>>(qkv, rel, at, S);
  gemm3<0,1><<<(BS/128)*(HID/128), 256, 0, stream>>>(
      at, Wpb, out, BS, HID, HID, nullptr, 1.0f, 1.0f);
}